// Round 7
// baseline (367.824 us; speedup 1.0000x reference)
//
#include <hip/hip_runtime.h>
#include <cstdint>
#include <cstddef>

#define HIDDEN 2048
#define HEADS 16
#define HD 128
#define BSZ 2
#define SEQ 2048
#define MTOT (BSZ * SEQ)        // 4096
#define NQKV (HIDDEN + 2 * HD)  // 2304
#define SL2E 0.12751743f        // (1/sqrt(128)) * log2(e)

typedef unsigned short ushort_t;
typedef __attribute__((ext_vector_type(8))) __bf16 bf16x8;
typedef __attribute__((ext_vector_type(4))) float f32x4;
typedef __attribute__((ext_vector_type(16))) float f32x16;

typedef __attribute__((address_space(3))) unsigned int as3_u32;
typedef __attribute__((address_space(1))) const unsigned int as1_u32;

// fp32 -> bf16 round-to-nearest-even
__device__ __forceinline__ ushort_t f2bf(float x) {
  union { float f; unsigned u; } v; v.f = x;
  unsigned r = v.u + 0x7fffu + ((v.u >> 16) & 1u);
  return (ushort_t)(r >> 16);
}
// pack two fp32 -> bf16x2 (truncation; bias cancels in normalized softmax)
__device__ __forceinline__ unsigned pk_bf16(float a, float b) {
  union { float f; unsigned u; } x, y; x.f = a; y.f = b;
  return (x.u >> 16) | (y.u & 0xFFFF0000u);
}

// async global->LDS, 16B per lane; lds dst is wave-uniform (HW adds lane*16)
__device__ __forceinline__ void gld16(const void* g, void* lds) {
  __builtin_amdgcn_global_load_lds((as1_u32*)g, (as3_u32*)lds, 16, 0, 0);
}

// ---------------------------------------------------------------------------
// Fused preprocessing: 5 independent kernels packed into one launch.
// Round-13: mask_flags blocks dispatched FIRST (each scans 32 KB -> ~8x the
// duration of a cvt block; long-pole-first removes them from the tail).
// Block ranges (all 256-thread, branch is block-uniform):
//   [0, NM)              mask_flags   per (b,q128,k64) 0/1/2
//   [NM, +N0)            cvt_bf16     X f32 -> Xb bf16 (float4/ushort4)
//   [.., +N1)            cvtT_qkv     Wq|Wk|Wv -> WT (2304x2048), Wq * SL2E
//   [.., +N2)            cvtT         Wo -> WoT (2048x2048)
//   [.., +N4)            concat_bias  biasQKV (Q-part * SL2E)
// ---------------------------------------------------------------------------
#define PREP_NM (32 * 16 * BSZ)                  // 1024
#define PREP_N0 (MTOT * HIDDEN / 4 / 256)        // 8192
#define PREP_N1 ((NQKV / 32) * (HIDDEN / 32))    // 4608
#define PREP_N2 ((HIDDEN / 32) * (HIDDEN / 32))  // 4096
#define PREP_N4 ((NQKV + 255) / 256)             // 9
#define PREP_NB (PREP_NM + PREP_N0 + PREP_N1 + PREP_N2 + PREP_N4)

__global__ __launch_bounds__(256) void prep_kernel(
    const float* __restrict__ X, ushort_t* __restrict__ Xb,
    const float* __restrict__ Wq, const float* __restrict__ Wk,
    const float* __restrict__ Wv, ushort_t* __restrict__ WT,
    const float* __restrict__ Wo, ushort_t* __restrict__ WoT,
    const int* __restrict__ mask, int* __restrict__ flags,
    const float* __restrict__ bq, const float* __restrict__ bk,
    const float* __restrict__ bv, float* __restrict__ biasQKV) {
  __shared__ float tileF[32][36];
  __shared__ int sAO[8];
  const int t = threadIdx.x;
  int j = blockIdx.x;

  if (j < PREP_NM) {  // ---- mask_flags (long-pole blocks first) ----
    const int kt = j & 31, qt = (j >> 5) & 15, b = j >> 9;
    int allv = 1, anyv = 0;
    const size_t base = (size_t)b * SEQ * SEQ + (size_t)qt * 128 * SEQ + kt * 64;
    for (int i = t; i < 2048; i += 256) {  // 128 rows x 16 int4
      const int row = i >> 4, c4 = (i & 15) << 2;
      const int4 v = *(const int4*)(mask + base + (size_t)row * SEQ + c4);
      const int nz = (v.x != 0) & (v.y != 0) & (v.z != 0) & (v.w != 0);
      const int nzany = (v.x != 0) | (v.y != 0) | (v.z != 0) | (v.w != 0);
      allv &= nz; anyv |= nzany;
    }
    const int wAll = __all(allv), wAny = __any(anyv);
    if ((t & 63) == 0) { sAO[t >> 6] = wAll; sAO[4 + (t >> 6)] = wAny; }
    __syncthreads();
    if (t == 0) {
      const int A = sAO[0] & sAO[1] & sAO[2] & sAO[3];
      const int O = sAO[4] | sAO[5] | sAO[6] | sAO[7];
      flags[(b * 16 + qt) * 32 + kt] = A ? 2 : (O ? 1 : 0);
    }
    return;
  }
  j -= PREP_NM;

  if (j < PREP_N0) {  // ---- cvt_bf16 (exact coverage, no bounds check) ----
    const int i = j * 256 + t;
    float4 v = ((const float4*)X)[i];
    ushort4 o;
    o.x = f2bf(v.x); o.y = f2bf(v.y); o.z = f2bf(v.z); o.w = f2bf(v.w);
    ((ushort4*)Xb)[i] = o;
    return;
  }
  j -= PREP_N0;

  if (j < PREP_N1) {  // ---- cvtT_qkv ----
    const int nb = (j % (NQKV / 32)) * 32, kb = (j / (NQKV / 32)) * 32;
    const float* W; int N, nc; float scale;
    if (nb < HIDDEN)           { W = Wq; N = HIDDEN; nc = nb;               scale = SL2E; }
    else if (nb < HIDDEN + HD) { W = Wk; N = HD;     nc = nb - HIDDEN;      scale = 1.f; }
    else                       { W = Wv; N = HD;     nc = nb - HIDDEN - HD; scale = 1.f; }
    {
      int row = t >> 3, c4 = (t & 7) << 2;
      float4 v = *(const float4*)(W + (size_t)(kb + row) * N + nc + c4);
      tileF[row][c4] = v.x * scale; tileF[row][c4 + 1] = v.y * scale;
      tileF[row][c4 + 2] = v.z * scale; tileF[row][c4 + 3] = v.w * scale;
    }
    __syncthreads();
    {
      int nl = t >> 3, k4 = (t & 7) << 2;
      ushort4 o;
      o.x = f2bf(tileF[k4 + 0][nl]); o.y = f2bf(tileF[k4 + 1][nl]);
      o.z = f2bf(tileF[k4 + 2][nl]); o.w = f2bf(tileF[k4 + 3][nl]);
      *(ushort4*)(WT + (size_t)(nb + nl) * HIDDEN + kb + k4) = o;
    }
    return;
  }
  j -= PREP_N1;

  if (j < PREP_N2) {  // ---- cvtT (Wo -> WoT), K=N=HIDDEN ----
    const int nb = (j % (HIDDEN / 32)) * 32, kb = (j / (HIDDEN / 32)) * 32;
    {
      int row = t >> 3, c4 = (t & 7) << 2;
      float4 v = *(const float4*)(Wo + (size_t)(kb + row) * HIDDEN + nb + c4);
      tileF[row][c4] = v.x; tileF[row][c4 + 1] = v.y;
      tileF[row][c4 + 2] = v.z; tileF[row][c4 + 3] = v.w;
    }
    __syncthreads();
    {
      int nl = t >> 3, k4 = (t & 7) << 2;
      ushort4 o;
      o.x = f2bf(tileF[k4 + 0][nl]); o.y = f2bf(tileF[k4 + 1][nl]);
      o.z = f2bf(tileF[k4 + 2][nl]); o.w = f2bf(tileF[k4 + 3][nl]);
      *(ushort4*)(WoT + (size_t)(nb + nl) * HIDDEN + kb + k4) = o;
    }
    return;
  }
  j -= PREP_N2;

  {  // ---- concat_bias ----
    const int i = j * 256 + t;
    if (i < NQKV)
      biasQKV[i] = (i < HIDDEN) ? bq[i] * SL2E
                 : (i < HIDDEN + HD ? bk[i - HIDDEN] : bv[i - HIDDEN - HD]);
  }
}

// V slice of QKV (4096 x 128, ld 2304) bf16 -> Vt (128 x 4096)
__global__ __launch_bounds__(256) void transpose_v_kernel(
    const ushort_t* __restrict__ Vin, ushort_t* __restrict__ Vt) {
  __shared__ ushort_t tile[32][40];
  const int t = threadIdx.x;
  const int rb = blockIdx.x * 32, cb = blockIdx.y * 32;
  {
    int row = t >> 3, c4 = (t & 7) << 2;
    ushort4 v = *(const ushort4*)(Vin + (size_t)(rb + row) * NQKV + cb + c4);
    tile[row][c4] = v.x; tile[row][c4 + 1] = v.y;
    tile[row][c4 + 2] = v.z; tile[row][c4 + 3] = v.w;
  }
  __syncthreads();
  {
    int dl = t >> 3, r4 = (t & 7) << 2;
    ushort4 o;
    o.x = tile[r4 + 0][dl]; o.y = tile[r4 + 1][dl];
    o.z = tile[r4 + 2][dl]; o.w = tile[r4 + 3][dl];
    *(ushort4*)(Vt + (size_t)(cb + dl) * MTOT + rb + r4) = o;
  }
}

// ---------------------------------------------------------------------------
// bf16 MFMA GEMM, 2-phase 128x128 double-buffered (round-3 proven config:
// 576/512 blocks -> 2+ blocks/CU; the 256^2 8-phase template regressed here
// because grid 144/128 < 256 CUs and 1 block/CU can't hide its barriers).
// ---------------------------------------------------------------------------
template <int OUTF32>
__global__ __launch_bounds__(256) void gemm_mfma(
    const ushort_t* __restrict__ A, const ushort_t* __restrict__ Bt,
    const float* __restrict__ bias, void* __restrict__ C,
    int M, int N, int K, int nm_per_xcd) {
  __shared__ ushort_t As[2][128 * 64];
  __shared__ ushort_t Bs[2][128 * 64];
  const int t = threadIdx.x;
  const int w = t >> 6, l = t & 63;
  const int id = blockIdx.x;
  const int xcd = id & 7, j = id >> 3;
  const int mt = xcd * nm_per_xcd + (j % nm_per_xcd);
  const int nt = j / nm_per_xcd;
  const int mb = mt * 128, nb = nt * 128;
  const int wm = (w >> 1) * 64, wn = (w & 1) * 64;
  const int fl = l & 15, g = l >> 4;
  const int srow = l >> 3, cphys = l & 7;

  f32x4 acc[4][4];
#pragma unroll
  for (int i = 0; i < 4; ++i)
#pragma unroll
    for (int jj = 0; jj < 4; ++jj) acc[i][jj] = (f32x4){0.f, 0.f, 0.f, 0.f};

#pragma unroll
  for (int jj = 0; jj < 4; ++jj) {
    const int inst = w * 4 + jj;
    const int row = inst * 8 + srow;
    const int clog = cphys ^ (row & 7);
    gld16(A + (size_t)(mb + row) * K + clog * 8, &As[0][inst * 512]);
    gld16(Bt + (size_t)(nb + row) * K + clog * 8, &Bs[0][inst * 512]);
  }

  int cur = 0;
  for (int k0 = 0; k0 < K; k0 += 64) {
    __syncthreads();
    if (k0 + 64 < K) {
#pragma unroll
      for (int jj = 0; jj < 4; ++jj) {
        const int inst = w * 4 + jj;
        const int row = inst * 8 + srow;
        const int clog = cphys ^ (row & 7);
        gld16(A + (size_t)(mb + row) * K + k0 + 64 + clog * 8,
              &As[cur ^ 1][inst * 512]);
        gld16(Bt + (size_t)(nb + row) * K + k0 + 64 + clog * 8,
              &Bs[cur ^ 1][inst * 512]);
      }
    }
    const ushort_t* Ac = &As[cur][0];
    const ushort_t* Bc = &Bs[cur][0];
#pragma unroll
    for (int s = 0; s < 2; ++s) {
      bf16x8 af[4], bfr[4];
#pragma unroll
      for (int i = 0; i < 4; ++i) {
        const int m = wm + i * 16 + fl;
        af[i] = *(const bf16x8*)&Ac[m * 64 + (((s << 2) + g) ^ (m & 7)) * 8];
        const int n = wn + i * 16 + fl;
        bfr[i] = *(const bf16x8*)&Bc[n * 64 + (((s << 2) + g) ^ (n & 7)) * 8];
      }
#pragma unroll
      for (int i = 0; i < 4; ++i)
#pragma unroll
        for (int jj = 0; jj < 4; ++jj)
          acc[i][jj] = __builtin_amdgcn_mfma_f32_16x16x32_bf16(
              af[i], bfr[jj], acc[i][jj], 0, 0, 0);
    }
    cur ^= 1;
  }

#pragma unroll
  for (int jj = 0; jj < 4; ++jj) {
    const int col = nb + wn + jj * 16 + fl;
    const float bv = bias[col];
#pragma unroll
    for (int i = 0; i < 4; ++i) {
      const int row0 = mb + wm + i * 16 + g * 4;
#pragma unroll
      for (int r = 0; r < 4; ++r) {
        const float val = acc[i][jj][r] + bv;
        if (OUTF32)
          ((float*)C)[(size_t)(row0 + r) * N + col] = val;
        else
          ((ushort_t*)C)[(size_t)(row0 + r) * N + col] = f2bf(val);
      }
    }
  }
}

// ---------------------------------------------------------------------------
// MFMA flash attention (unchanged: 82 us on healthy nodes, 0 bank conflicts).
// ---------------------------------------------------------------------------
__global__ __launch_bounds__(256, 2) void flash_mfma(
    const ushort_t* __restrict__ QKV,  // (4096, 2304) bf16; Q pre-scaled
    const ushort_t* __restrict__ Vt,   // (128, 4096) bf16
    const int* __restrict__ mask,      // (B, S, S)
    const int* __restrict__ flags,     // (B, 16, 32)
    ushort_t* __restrict__ Ab)         // (4096, 2048) bf16
{
  __shared__ ushort_t Kbuf[2][64 * 128];  // 32 KB: key rows x 128 k-dim
  __shared__ ushort_t Vbuf[2][64 * 128];  // 32 KB: paired-d rows x (2x8) chunks

  const int qt = blockIdx.x, h = blockIdx.y, b = blockIdx.z;
  const int t = threadIdx.x, w = t >> 6, l = t & 63;
  const int q31 = l & 31, hi = l >> 5;
  const int qbase = qt * 128;
  const int qrow = qbase + w * 32 + q31;  // within-batch q row (B-col index)

  // Q as B-fragments: col=q31, k = ks*16 + hi*8 + j (exp2 domain, pre-scaled)
  bf16x8 qf[8];
#pragma unroll
  for (int ks = 0; ks < 8; ++ks)
    qf[ks] = *(const bf16x8*)(QKV + (size_t)(b * SEQ + qrow) * NQKV + h * HD +
                              ks * 16 + hi * 8);

  // ones B-frag for l: B[col=q31][k] = (q31==0) ? 1.0 : 0
  bf16x8 onesf;
  {
    const ushort_t ov = (q31 == 0) ? (ushort_t)0x3F80 : (ushort_t)0;
#pragma unroll
    for (int jj = 0; jj < 8; ++jj) ((ushort_t*)&onesf)[jj] = ov;
  }

  // prologue: prefetch K(0),V(0) -> buffer 0
#pragma unroll
  for (int j = 0; j < 4; ++j) {
    const int inst = w * 4 + j;
    // K: 256B rows; phys chunk (l&15) holds logical (l&15)^(krow&15)
    const int krow = inst * 4 + (l >> 4);
    const int ck = (l & 15) ^ (krow & 15);
    gld16(QKV + (size_t)(b * SEQ + krow) * NQKV + HIDDEN + ck * 8,
          &Kbuf[0][inst * 512]);
    // V: LDS row r holds d=2r,2r+1; phys p = clog ^ (r&15), clog=(d&1)*8+kc
    const int vr = inst * 4 + (l >> 4);
    const int clog = (l & 15) ^ (vr & 15);
    const int d = 2 * vr + (clog >> 3);
    gld16(Vt + (size_t)d * MTOT + b * SEQ + (clog & 7) * 8,
          &Vbuf[0][inst * 512]);
  }

  const size_t mbase = (size_t)b * SEQ * SEQ;

  f32x16 oacc[4], lacc;
#pragma unroll
  for (int d = 0; d < 4; ++d)
#pragma unroll
    for (int r = 0; r < 16; ++r) oacc[d][r] = 0.f;
#pragma unroll
  for (int r = 0; r < 16; ++r) lacc[r] = 0.f;

  int cur = 0;
  for (int kt = 0; kt < SEQ / 64; ++kt) {
    const int kbase = kt * 64;
    const int flag = flags[((b * 16 + qt) << 5) + kt];  // block-uniform
    __syncthreads();  // buf[cur] DMAs drained; prev tile done with buf[cur^1]

    // prefetch K(kt+1), V(kt+1) -> buf[cur^1] (clamped on last tile)
    {
      const int knb = (kt + 1 < SEQ / 64) ? (kbase + 64) : kbase;
#pragma unroll
      for (int j = 0; j < 4; ++j) {
        const int inst = w * 4 + j;
        const int krow = inst * 4 + (l >> 4);
        const int ck = (l & 15) ^ (krow & 15);
        gld16(QKV + (size_t)(b * SEQ + knb + krow) * NQKV + HIDDEN + ck * 8,
              &Kbuf[cur ^ 1][inst * 512]);
        const int vr = inst * 4 + (l >> 4);
        const int clog = (l & 15) ^ (vr & 15);
        const int d = 2 * vr + (clog >> 3);
        gld16(Vt + (size_t)d * MTOT + b * SEQ + knb + (clog & 7) * 8,
              &Vbuf[cur ^ 1][inst * 512]);
      }
    }

    // ---- S^T = K·Q^T from Kbuf[cur]: A = K rows (key), B = Q cols (q) ----
    const ushort_t* Kc = &Kbuf[cur][0];
    f32x16 sc[2];
#pragma unroll
    for (int kk = 0; kk < 2; ++kk)
#pragma unroll
      for (int r = 0; r < 16; ++r) sc[kk][r] = 0.f;

    __builtin_amdgcn_s_setprio(1);
#pragma unroll
    for (int ks = 0; ks < 8; ++ks)
#pragma unroll
      for (int kk = 0; kk < 2; ++kk) {
        const int key = kk * 32 + q31;  // A-row = lane&31
        const bf16x8 kf = *(const bf16x8*)&Kc[key * 128 +
                                              (((ks << 1) + hi) ^ (key & 15)) * 8];
        sc[kk] = __builtin_amdgcn_mfma_f32_32x32x16_bf16(kf, qf[ks], sc[kk],
                                                         0, 0, 0);
      }
    __builtin_amdgcn_s_setprio(0);

    if (flag != 2) {  // mixed/empty tile: per-element mask fallback
#pragma unroll
      for (int kk = 0; kk < 2; ++kk)
#pragma unroll
        for (int r = 0; r < 16; ++r) {
          const int key = kbase + kk * 32 + (r & 3) + ((r >> 2) << 3) + (hi << 2);
          if (!mask[mbase + (size_t)qrow * SEQ + key]) sc[kk][r] = -1e30f;
        }
    }

    // ---- P = exp2(S^T); pack bf16; permlane32_swap -> PA A-frags in regs ----
    bf16x8 pa[4];
#pragma unroll
    for (int kk = 0; kk < 2; ++kk) {
      float pv[16];
#pragma unroll
      for (int r = 0; r < 16; ++r) pv[r] = __builtin_amdgcn_exp2f(sc[kk][r]);
#pragma unroll
      for (int half = 0; half < 2; ++half) {
        const int bs = half * 8;
        unsigned a0 = pk_bf16(pv[bs + 0], pv[bs + 1]);
        unsigned a1 = pk_bf16(pv[bs + 2], pv[bs + 3]);
        unsigned b0 = pk_bf16(pv[bs + 4], pv[bs + 5]);
        unsigned b1 = pk_bf16(pv[bs + 6], pv[bs + 7]);
        asm("v_permlane32_swap_b32 %0, %1" : "+v"(a0), "+v"(b0));
        asm("v_permlane32_swap_b32 %0, %1" : "+v"(a1), "+v"(b1));
        union { unsigned u[4]; bf16x8 v; } uu;
        uu.u[0] = a0; uu.u[1] = a1; uu.u[2] = b0; uu.u[3] = b1;
        pa[kk * 2 + half] = uu.v;
      }
    }

    // ---- O += P·V (B-frags from Vbuf[cur], paired-row layout); l += P·ones --
    const ushort_t* Vc = &Vbuf[cur][0];
    __builtin_amdgcn_s_setprio(1);
#pragma unroll
    for (int ks = 0; ks < 4; ++ks) {
#pragma unroll
      for (int dt = 0; dt < 4; ++dt) {
        const int d = dt * 32 + q31;  // B-col = lane&31
        const int vr = d >> 1;
        const int clog = ((d & 1) << 3) + (ks << 1) + hi;
        const bf16x8 vf =
            *(const bf16x8*)&Vc[vr * 128 + (clog ^ (vr & 15)) * 8];
        oacc[dt] = __builtin_amdgcn_mfma_f32_32x32x16_bf16(pa[ks], vf,
                                                           oacc[dt], 0, 0, 0);
      }
      lacc = __builtin_amdgcn_mfma_f32_32x32x16_bf16(pa[ks], onesf, lacc,
                                                     0, 0, 0);
    }
    __builtin_amdgcn_s_setprio(0);
    cur ^= 1;
  }

  // ---- epilogue: l lives in col 0 (lanes 0 and 32); D row = q = crow ----
#pragma unroll
  for (int r = 0; r < 16; ++r) {
    const float ls = __shfl(lacc[r], l & 32, 64);
    const float invl = 1.0f / ls;
    const int row = b * SEQ + qbase + w * 32 + (r & 3) + ((r >> 2) << 3) +
                    (hi << 2);
#pragma unroll
    for (int dt = 0; dt < 4; ++dt)
      Ab[(size_t)row * HIDDEN + h * HD + dt * 32 + q31] =
          f2bf(oacc[dt][r] * invl);
  }
}

// ---------------------------------------------------------------------------
extern "C" void kernel_launch(void* const* d_in, const int* in_sizes, int n_in,
                              void* d_out, int out_size, void* d_ws, size_t ws_size,
                              hipStream_t stream) {
  const float* X  = (const float*)d_in[0];
  const int* mask = (const int*)d_in[1];
  const float* Wq = (const float*)d_in[2];
  const float* bq = (const float*)d_in[3];
  const float* Wk = (const float*)d_in[4];
  const float* bk = (const float*)d_in[5];
  const float* Wv = (const float*)d_in[6];
  const float* bv = (const float*)d_in[7];
  const float* Wo = (const float*)d_in[8];
  const float* bo = (const float*)d_in[9];
  float* out = (float*)d_out;

  char* p = (char*)d_ws;
  ushort_t* QKVb = (ushort_t*)p; p += (size_t)MTOT * NQKV * 2;
  ushort_t* Xb   = (ushort_t*)p; p += (size_t)MTOT * HIDDEN * 2;  // reused as Ab
  ushort_t* WT   = (ushort_t*)p; p += (size_t)NQKV * HIDDEN * 2;
  ushort_t* WoT  = (ushort_t*)p; p += (size_t)HIDDEN * HIDDEN * 2;
  ushort_t* Vt   = (ushort_t*)p; p += (size_t)HD * MTOT * 2;
  float* biasQKV = (float*)p;    p += 4096;
  int* flags     = (int*)p;      p += BSZ * 16 * 32 * 4;
  ushort_t* Ab = Xb;  // X consumed by QKV GEMM before flash writes Ab

  // fused preprocessing (mask flags first, then cvt/transposes/bias)
  prep_kernel<<<PREP_NB, 256, 0, stream>>>(
      X, Xb, Wq, Wk, Wv, WT, Wo, WoT, mask, flags, bq, bk, bv, biasQKV);

  // QKV projection: M=4096 (32 m-tiles), N=2304 (18 n-tiles); nm/8 = 4
  gemm_mfma<0><<<dim3((MTOT / 128) * (NQKV / 128)), 256, 0, stream>>>(
      Xb, WT, biasQKV, QKVb, MTOT, NQKV, HIDDEN, (MTOT / 128) / 8);
  transpose_v_kernel<<<dim3(MTOT / 32, HD / 32), 256, 0, stream>>>(
      QKVb + HIDDEN + HD, Vt);
  flash_mfma<<<dim3(SEQ / 128, HEADS, BSZ), 256, 0, stream>>>(
      QKVb, Vt, mask, flags, Ab);
  // O projection: M=4096 (32 m-tiles), N=2048 (16 n-tiles)
  gemm_mfma<1><<<dim3((MTOT / 128) * (HIDDEN / 128)), 256, 0, stream>>>(
      Ab, WoT, bo, out, MTOT, HIDDEN, HIDDEN, (MTOT / 128) / 8);
}

// Round 9
// 329.201 us; speedup vs baseline: 1.1173x; 1.1173x over previous
//
#include <hip/hip_runtime.h>
#include <cstdint>
#include <cstddef>

#define HIDDEN 2048
#define HEADS 16
#define HD 128
#define BSZ 2
#define SEQ 2048
#define MTOT (BSZ * SEQ)        // 4096
#define NQKV (HIDDEN + 2 * HD)  // 2304
#define SL2E 0.12751743f        // (1/sqrt(128)) * log2(e)

typedef unsigned short ushort_t;
typedef __attribute__((ext_vector_type(8))) __bf16 bf16x8;
typedef __attribute__((ext_vector_type(4))) float f32x4;
typedef __attribute__((ext_vector_type(16))) float f32x16;

typedef __attribute__((address_space(3))) unsigned int as3_u32;
typedef __attribute__((address_space(1))) const unsigned int as1_u32;

// fp32 -> bf16 round-to-nearest-even
__device__ __forceinline__ ushort_t f2bf(float x) {
  union { float f; unsigned u; } v; v.f = x;
  unsigned r = v.u + 0x7fffu + ((v.u >> 16) & 1u);
  return (ushort_t)(r >> 16);
}
// pack two fp32 -> bf16x2 (truncation; bias cancels in normalized softmax)
__device__ __forceinline__ unsigned pk_bf16(float a, float b) {
  union { float f; unsigned u; } x, y; x.f = a; y.f = b;
  return (x.u >> 16) | (y.u & 0xFFFF0000u);
}

// async global->LDS, 16B per lane; lds dst is wave-uniform (HW adds lane*16)
__device__ __forceinline__ void gld16(const void* g, void* lds) {
  __builtin_amdgcn_global_load_lds((as1_u32*)g, (as3_u32*)lds, 16, 0, 0);
}

// ---------------------------------------------------------------------------
// Fused preprocessing: 5 independent kernels packed into one launch.
// ROOT-CAUSE NOTE (rounds 6-8): biasQKV was allocated 4096 BYTES but holds
// NQKV=2304 floats = 9216 bytes. The 5120-byte overrun clobbered whatever
// followed it in the workspace (flags in r6/r7 -> flash silently took the
// mask-fallback path, FETCH 16.5->32.9MB; QKVb in r8 -> wrong results).
// Fixed by reserving 16KB for biasQKV. With disjoint regions this fusion is
// sound. mask_flags blocks first (long-pole-first: each scans 32KB).
// Block ranges (all 256-thread, branch is block-uniform):
//   [0, NM)              mask_flags   per (b,q128,k64) 0/1/2
//   [NM, +N0)            cvt_bf16     X f32 -> Xb bf16 (float4/ushort4)
//   [.., +N1)            cvtT_qkv     Wq|Wk|Wv -> WT (2304x2048), Wq * SL2E
//   [.., +N2)            cvtT         Wo -> WoT (2048x2048)
//   [.., +N4)            concat_bias  biasQKV (Q-part * SL2E)
// ---------------------------------------------------------------------------
#define PREP_NM (32 * 16 * BSZ)                  // 1024
#define PREP_N0 (MTOT * HIDDEN / 4 / 256)        // 8192
#define PREP_N1 ((NQKV / 32) * (HIDDEN / 32))    // 4608
#define PREP_N2 ((HIDDEN / 32) * (HIDDEN / 32))  // 4096
#define PREP_N4 ((NQKV + 255) / 256)             // 9
#define PREP_NB (PREP_NM + PREP_N0 + PREP_N1 + PREP_N2 + PREP_N4)

__global__ __launch_bounds__(256) void prep_kernel(
    const float* __restrict__ X, ushort_t* __restrict__ Xb,
    const float* __restrict__ Wq, const float* __restrict__ Wk,
    const float* __restrict__ Wv, ushort_t* __restrict__ WT,
    const float* __restrict__ Wo, ushort_t* __restrict__ WoT,
    const int* __restrict__ mask, int* __restrict__ flags,
    const float* __restrict__ bq, const float* __restrict__ bk,
    const float* __restrict__ bv, float* __restrict__ biasQKV) {
  __shared__ float tileF[32][36];
  __shared__ int sAO[8];
  const int t = threadIdx.x;
  int j = blockIdx.x;

  if (j < PREP_NM) {  // ---- mask_flags (long-pole blocks first) ----
    const int kt = j & 31, qt = (j >> 5) & 15, b = j >> 9;
    int allv = 1, anyv = 0;
    const size_t base = (size_t)b * SEQ * SEQ + (size_t)qt * 128 * SEQ + kt * 64;
    for (int i = t; i < 2048; i += 256) {  // 128 rows x 16 int4
      const int row = i >> 4, c4 = (i & 15) << 2;
      const int4 v = *(const int4*)(mask + base + (size_t)row * SEQ + c4);
      const int nz = (v.x != 0) & (v.y != 0) & (v.z != 0) & (v.w != 0);
      const int nzany = (v.x != 0) | (v.y != 0) | (v.z != 0) | (v.w != 0);
      allv &= nz; anyv |= nzany;
    }
    const int wAll = __all(allv), wAny = __any(anyv);
    if ((t & 63) == 0) { sAO[t >> 6] = wAll; sAO[4 + (t >> 6)] = wAny; }
    __syncthreads();
    if (t == 0) {
      const int A = sAO[0] & sAO[1] & sAO[2] & sAO[3];
      const int O = sAO[4] | sAO[5] | sAO[6] | sAO[7];
      flags[(b * 16 + qt) * 32 + kt] = A ? 2 : (O ? 1 : 0);
    }
    return;
  }
  j -= PREP_NM;

  if (j < PREP_N0) {  // ---- cvt_bf16 (exact coverage, no bounds check) ----
    const int i = j * 256 + t;
    float4 v = ((const float4*)X)[i];
    ushort4 o;
    o.x = f2bf(v.x); o.y = f2bf(v.y); o.z = f2bf(v.z); o.w = f2bf(v.w);
    ((ushort4*)Xb)[i] = o;
    return;
  }
  j -= PREP_N0;

  if (j < PREP_N1) {  // ---- cvtT_qkv ----
    const int nb = (j % (NQKV / 32)) * 32, kb = (j / (NQKV / 32)) * 32;
    const float* W; int N, nc; float scale;
    if (nb < HIDDEN)           { W = Wq; N = HIDDEN; nc = nb;               scale = SL2E; }
    else if (nb < HIDDEN + HD) { W = Wk; N = HD;     nc = nb - HIDDEN;      scale = 1.f; }
    else                       { W = Wv; N = HD;     nc = nb - HIDDEN - HD; scale = 1.f; }
    {
      int row = t >> 3, c4 = (t & 7) << 2;
      float4 v = *(const float4*)(W + (size_t)(kb + row) * N + nc + c4);
      tileF[row][c4] = v.x * scale; tileF[row][c4 + 1] = v.y * scale;
      tileF[row][c4 + 2] = v.z * scale; tileF[row][c4 + 3] = v.w * scale;
    }
    __syncthreads();
    {
      int nl = t >> 3, k4 = (t & 7) << 2;
      ushort4 o;
      o.x = f2bf(tileF[k4 + 0][nl]); o.y = f2bf(tileF[k4 + 1][nl]);
      o.z = f2bf(tileF[k4 + 2][nl]); o.w = f2bf(tileF[k4 + 3][nl]);
      *(ushort4*)(WT + (size_t)(nb + nl) * HIDDEN + kb + k4) = o;
    }
    return;
  }
  j -= PREP_N1;

  if (j < PREP_N2) {  // ---- cvtT (Wo -> WoT), K=N=HIDDEN ----
    const int nb = (j % (HIDDEN / 32)) * 32, kb = (j / (HIDDEN / 32)) * 32;
    {
      int row = t >> 3, c4 = (t & 7) << 2;
      float4 v = *(const float4*)(Wo + (size_t)(kb + row) * HIDDEN + nb + c4);
      tileF[row][c4] = v.x; tileF[row][c4 + 1] = v.y;
      tileF[row][c4 + 2] = v.z; tileF[row][c4 + 3] = v.w;
    }
    __syncthreads();
    {
      int nl = t >> 3, k4 = (t & 7) << 2;
      ushort4 o;
      o.x = f2bf(tileF[k4 + 0][nl]); o.y = f2bf(tileF[k4 + 1][nl]);
      o.z = f2bf(tileF[k4 + 2][nl]); o.w = f2bf(tileF[k4 + 3][nl]);
      *(ushort4*)(WoT + (size_t)(nb + nl) * HIDDEN + kb + k4) = o;
    }
    return;
  }
  j -= PREP_N2;

  {  // ---- concat_bias ----
    const int i = j * 256 + t;
    if (i < NQKV)
      biasQKV[i] = (i < HIDDEN) ? bq[i] * SL2E
                 : (i < HIDDEN + HD ? bk[i - HIDDEN] : bv[i - HIDDEN - HD]);
  }
}

// V slice of QKV (4096 x 128, ld 2304) bf16 -> Vt (128 x 4096)
__global__ __launch_bounds__(256) void transpose_v_kernel(
    const ushort_t* __restrict__ Vin, ushort_t* __restrict__ Vt) {
  __shared__ ushort_t tile[32][40];
  const int t = threadIdx.x;
  const int rb = blockIdx.x * 32, cb = blockIdx.y * 32;
  {
    int row = t >> 3, c4 = (t & 7) << 2;
    ushort4 v = *(const ushort4*)(Vin + (size_t)(rb + row) * NQKV + cb + c4);
    tile[row][c4] = v.x; tile[row][c4 + 1] = v.y;
    tile[row][c4 + 2] = v.z; tile[row][c4 + 3] = v.w;
  }
  __syncthreads();
  {
    int dl = t >> 3, r4 = (t & 7) << 2;
    ushort4 o;
    o.x = tile[r4 + 0][dl]; o.y = tile[r4 + 1][dl];
    o.z = tile[r4 + 2][dl]; o.w = tile[r4 + 3][dl];
    *(ushort4*)(Vt + (size_t)(cb + dl) * MTOT + rb + r4) = o;
  }
}

// ---------------------------------------------------------------------------
// bf16 MFMA GEMM, 2-phase 128x128 double-buffered (round-3 proven config:
// 576/512 blocks -> 2+ blocks/CU).
// ---------------------------------------------------------------------------
template <int OUTF32>
__global__ __launch_bounds__(256) void gemm_mfma(
    const ushort_t* __restrict__ A, const ushort_t* __restrict__ Bt,
    const float* __restrict__ bias, void* __restrict__ C,
    int M, int N, int K, int nm_per_xcd) {
  __shared__ ushort_t As[2][128 * 64];
  __shared__ ushort_t Bs[2][128 * 64];
  const int t = threadIdx.x;
  const int w = t >> 6, l = t & 63;
  const int id = blockIdx.x;
  const int xcd = id & 7, j = id >> 3;
  const int mt = xcd * nm_per_xcd + (j % nm_per_xcd);
  const int nt = j / nm_per_xcd;
  const int mb = mt * 128, nb = nt * 128;
  const int wm = (w >> 1) * 64, wn = (w & 1) * 64;
  const int fl = l & 15, g = l >> 4;
  const int srow = l >> 3, cphys = l & 7;

  f32x4 acc[4][4];
#pragma unroll
  for (int i = 0; i < 4; ++i)
#pragma unroll
    for (int jj = 0; jj < 4; ++jj) acc[i][jj] = (f32x4){0.f, 0.f, 0.f, 0.f};

#pragma unroll
  for (int jj = 0; jj < 4; ++jj) {
    const int inst = w * 4 + jj;
    const int row = inst * 8 + srow;
    const int clog = cphys ^ (row & 7);
    gld16(A + (size_t)(mb + row) * K + clog * 8, &As[0][inst * 512]);
    gld16(Bt + (size_t)(nb + row) * K + clog * 8, &Bs[0][inst * 512]);
  }

  int cur = 0;
  for (int k0 = 0; k0 < K; k0 += 64) {
    __syncthreads();
    if (k0 + 64 < K) {
#pragma unroll
      for (int jj = 0; jj < 4; ++jj) {
        const int inst = w * 4 + jj;
        const int row = inst * 8 + srow;
        const int clog = cphys ^ (row & 7);
        gld16(A + (size_t)(mb + row) * K + k0 + 64 + clog * 8,
              &As[cur ^ 1][inst * 512]);
        gld16(Bt + (size_t)(nb + row) * K + k0 + 64 + clog * 8,
              &Bs[cur ^ 1][inst * 512]);
      }
    }
    const ushort_t* Ac = &As[cur][0];
    const ushort_t* Bc = &Bs[cur][0];
#pragma unroll
    for (int s = 0; s < 2; ++s) {
      bf16x8 af[4], bfr[4];
#pragma unroll
      for (int i = 0; i < 4; ++i) {
        const int m = wm + i * 16 + fl;
        af[i] = *(const bf16x8*)&Ac[m * 64 + (((s << 2) + g) ^ (m & 7)) * 8];
        const int n = wn + i * 16 + fl;
        bfr[i] = *(const bf16x8*)&Bc[n * 64 + (((s << 2) + g) ^ (n & 7)) * 8];
      }
#pragma unroll
      for (int i = 0; i < 4; ++i)
#pragma unroll
        for (int jj = 0; jj < 4; ++jj)
          acc[i][jj] = __builtin_amdgcn_mfma_f32_16x16x32_bf16(
              af[i], bfr[jj], acc[i][jj], 0, 0, 0);
    }
    cur ^= 1;
  }

#pragma unroll
  for (int jj = 0; jj < 4; ++jj) {
    const int col = nb + wn + jj * 16 + fl;
    const float bv = bias[col];
#pragma unroll
    for (int i = 0; i < 4; ++i) {
      const int row0 = mb + wm + i * 16 + g * 4;
#pragma unroll
      for (int r = 0; r < 4; ++r) {
        const float val = acc[i][jj][r] + bv;
        if (OUTF32)
          ((float*)C)[(size_t)(row0 + r) * N + col] = val;
        else
          ((ushort_t*)C)[(size_t)(row0 + r) * N + col] = f2bf(val);
      }
    }
  }
}

// ---------------------------------------------------------------------------
// MFMA flash attention (unchanged: 82 us with valid flags, 0 bank conflicts).
// ---------------------------------------------------------------------------
__global__ __launch_bounds__(256, 2) void flash_mfma(
    const ushort_t* __restrict__ QKV,  // (4096, 2304) bf16; Q pre-scaled
    const ushort_t* __restrict__ Vt,   // (128, 4096) bf16
    const int* __restrict__ mask,      // (B, S, S)
    const int* __restrict__ flags,     // (B, 16, 32)
    ushort_t* __restrict__ Ab)         // (4096, 2048) bf16
{
  __shared__ ushort_t Kbuf[2][64 * 128];  // 32 KB: key rows x 128 k-dim
  __shared__ ushort_t Vbuf[2][64 * 128];  // 32 KB: paired-d rows x (2x8) chunks

  const int qt = blockIdx.x, h = blockIdx.y, b = blockIdx.z;
  const int t = threadIdx.x, w = t >> 6, l = t & 63;
  const int q31 = l & 31, hi = l >> 5;
  const int qbase = qt * 128;
  const int qrow = qbase + w * 32 + q31;  // within-batch q row (B-col index)

  // Q as B-fragments: col=q31, k = ks*16 + hi*8 + j (exp2 domain, pre-scaled)
  bf16x8 qf[8];
#pragma unroll
  for (int ks = 0; ks < 8; ++ks)
    qf[ks] = *(const bf16x8*)(QKV + (size_t)(b * SEQ + qrow) * NQKV + h * HD +
                              ks * 16 + hi * 8);

  // ones B-frag for l: B[col=q31][k] = (q31==0) ? 1.0 : 0
  bf16x8 onesf;
  {
    const ushort_t ov = (q31 == 0) ? (ushort_t)0x3F80 : (ushort_t)0;
#pragma unroll
    for (int jj = 0; jj < 8; ++jj) ((ushort_t*)&onesf)[jj] = ov;
  }

  // prologue: prefetch K(0),V(0) -> buffer 0
#pragma unroll
  for (int j = 0; j < 4; ++j) {
    const int inst = w * 4 + j;
    // K: 256B rows; phys chunk (l&15) holds logical (l&15)^(krow&15)
    const int krow = inst * 4 + (l >> 4);
    const int ck = (l & 15) ^ (krow & 15);
    gld16(QKV + (size_t)(b * SEQ + krow) * NQKV + HIDDEN + ck * 8,
          &Kbuf[0][inst * 512]);
    // V: LDS row r holds d=2r,2r+1; phys p = clog ^ (r&15), clog=(d&1)*8+kc
    const int vr = inst * 4 + (l >> 4);
    const int clog = (l & 15) ^ (vr & 15);
    const int d = 2 * vr + (clog >> 3);
    gld16(Vt + (size_t)d * MTOT + b * SEQ + (clog & 7) * 8,
          &Vbuf[0][inst * 512]);
  }

  const size_t mbase = (size_t)b * SEQ * SEQ;

  f32x16 oacc[4], lacc;
#pragma unroll
  for (int d = 0; d < 4; ++d)
#pragma unroll
    for (int r = 0; r < 16; ++r) oacc[d][r] = 0.f;
#pragma unroll
  for (int r = 0; r < 16; ++r) lacc[r] = 0.f;

  int cur = 0;
  for (int kt = 0; kt < SEQ / 64; ++kt) {
    const int kbase = kt * 64;
    const int flag = flags[((b * 16 + qt) << 5) + kt];  // block-uniform
    __syncthreads();  // buf[cur] DMAs drained; prev tile done with buf[cur^1]

    // prefetch K(kt+1), V(kt+1) -> buf[cur^1] (clamped on last tile)
    {
      const int knb = (kt + 1 < SEQ / 64) ? (kbase + 64) : kbase;
#pragma unroll
      for (int j = 0; j < 4; ++j) {
        const int inst = w * 4 + j;
        const int krow = inst * 4 + (l >> 4);
        const int ck = (l & 15) ^ (krow & 15);
        gld16(QKV + (size_t)(b * SEQ + knb + krow) * NQKV + HIDDEN + ck * 8,
              &Kbuf[cur ^ 1][inst * 512]);
        const int vr = inst * 4 + (l >> 4);
        const int clog = (l & 15) ^ (vr & 15);
        const int d = 2 * vr + (clog >> 3);
        gld16(Vt + (size_t)d * MTOT + b * SEQ + knb + (clog & 7) * 8,
              &Vbuf[cur ^ 1][inst * 512]);
      }
    }

    // ---- S^T = K·Q^T from Kbuf[cur]: A = K rows (key), B = Q cols (q) ----
    const ushort_t* Kc = &Kbuf[cur][0];
    f32x16 sc[2];
#pragma unroll
    for (int kk = 0; kk < 2; ++kk)
#pragma unroll
      for (int r = 0; r < 16; ++r) sc[kk][r] = 0.f;

    __builtin_amdgcn_s_setprio(1);
#pragma unroll
    for (int ks = 0; ks < 8; ++ks)
#pragma unroll
      for (int kk = 0; kk < 2; ++kk) {
        const int key = kk * 32 + q31;  // A-row = lane&31
        const bf16x8 kf = *(const bf16x8*)&Kc[key * 128 +
                                              (((ks << 1) + hi) ^ (key & 15)) * 8];
        sc[kk] = __builtin_amdgcn_mfma_f32_32x32x16_bf16(kf, qf[ks], sc[kk],
                                                         0, 0, 0);
      }
    __builtin_amdgcn_s_setprio(0);

    if (flag != 2) {  // mixed/empty tile: per-element mask fallback
#pragma unroll
      for (int kk = 0; kk < 2; ++kk)
#pragma unroll
        for (int r = 0; r < 16; ++r) {
          const int key = kbase + kk * 32 + (r & 3) + ((r >> 2) << 3) + (hi << 2);
          if (!mask[mbase + (size_t)qrow * SEQ + key]) sc[kk][r] = -1e30f;
        }
    }

    // ---- P = exp2(S^T); pack bf16; permlane32_swap -> PA A-frags in regs ----
    bf16x8 pa[4];
#pragma unroll
    for (int kk = 0; kk < 2; ++kk) {
      float pv[16];
#pragma unroll
      for (int r = 0; r < 16; ++r) pv[r] = __builtin_amdgcn_exp2f(sc[kk][r]);
#pragma unroll
      for (int half = 0; half < 2; ++half) {
        const int bs = half * 8;
        unsigned a0 = pk_bf16(pv[bs + 0], pv[bs + 1]);
        unsigned a1 = pk_bf16(pv[bs + 2], pv[bs + 3]);
        unsigned b0 = pk_bf16(pv[bs + 4], pv[bs + 5]);
        unsigned b1 = pk_bf16(pv[bs + 6], pv[bs + 7]);
        asm("v_permlane32_swap_b32 %0, %1" : "+v"(a0), "+v"(b0));
        asm("v_permlane32_swap_b32 %0, %1" : "+v"(a1), "+v"(b1));
        union { unsigned u[4]; bf16x8 v; } uu;
        uu.u[0] = a0; uu.u[1] = a1; uu.u[2] = b0; uu.u[3] = b1;
        pa[kk * 2 + half] = uu.v;
      }
    }

    // ---- O += P·V (B-frags from Vbuf[cur], paired-row layout); l += P·ones --
    const ushort_t* Vc = &Vbuf[cur][0];
    __builtin_amdgcn_s_setprio(1);
#pragma unroll
    for (int ks = 0; ks < 4; ++ks) {
#pragma unroll
      for (int dt = 0; dt < 4; ++dt) {
        const int d = dt * 32 + q31;  // B-col = lane&31
        const int vr = d >> 1;
        const int clog = ((d & 1) << 3) + (ks << 1) + hi;
        const bf16x8 vf =
            *(const bf16x8*)&Vc[vr * 128 + (clog ^ (vr & 15)) * 8];
        oacc[dt] = __builtin_amdgcn_mfma_f32_32x32x16_bf16(pa[ks], vf,
                                                           oacc[dt], 0, 0, 0);
      }
      lacc = __builtin_amdgcn_mfma_f32_32x32x16_bf16(pa[ks], onesf, lacc,
                                                     0, 0, 0);
    }
    __builtin_amdgcn_s_setprio(0);
    cur ^= 1;
  }

  // ---- epilogue: l lives in col 0 (lanes 0 and 32); D row = q = crow ----
#pragma unroll
  for (int r = 0; r < 16; ++r) {
    const float ls = __shfl(lacc[r], l & 32, 64);
    const float invl = 1.0f / ls;
    const int row = b * SEQ + qbase + w * 32 + (r & 3) + ((r >> 2) << 3) +
                    (hi << 2);
#pragma unroll
    for (int dt = 0; dt < 4; ++dt)
      Ab[(size_t)row * HIDDEN + h * HD + dt * 32 + q31] =
          f2bf(oacc[dt][r] * invl);
  }
}

// ---------------------------------------------------------------------------
extern "C" void kernel_launch(void* const* d_in, const int* in_sizes, int n_in,
                              void* d_out, int out_size, void* d_ws, size_t ws_size,
                              hipStream_t stream) {
  const float* X  = (const float*)d_in[0];
  const int* mask = (const int*)d_in[1];
  const float* Wq = (const float*)d_in[2];
  const float* bq = (const float*)d_in[3];
  const float* Wk = (const float*)d_in[4];
  const float* bk = (const float*)d_in[5];
  const float* Wv = (const float*)d_in[6];
  const float* bv = (const float*)d_in[7];
  const float* Wo = (const float*)d_in[8];
  const float* bo = (const float*)d_in[9];
  float* out = (float*)d_out;

  char* p = (char*)d_ws;
  int* flags     = (int*)p;      p += BSZ * 16 * 32 * 4;   // 4 KB
  float* biasQKV = (float*)p;    p += 16384;  // NQKV floats = 9216 B; 16 KB reserved
  ushort_t* QKVb = (ushort_t*)p; p += (size_t)MTOT * NQKV * 2;
  ushort_t* Xb   = (ushort_t*)p; p += (size_t)MTOT * HIDDEN * 2;  // reused as Ab
  ushort_t* WT   = (ushort_t*)p; p += (size_t)NQKV * HIDDEN * 2;
  ushort_t* WoT  = (ushort_t*)p; p += (size_t)HIDDEN * HIDDEN * 2;
  ushort_t* Vt   = (ushort_t*)p; p += (size_t)HD * MTOT * 2;
  ushort_t* Ab = Xb;  // X consumed by QKV GEMM before flash writes Ab

  // fused preprocessing (mask flags, cvt, weight transposes, bias)
  prep_kernel<<<PREP_NB, 256, 0, stream>>>(
      X, Xb, Wq, Wk, Wv, WT, Wo, WoT, mask, flags, bq, bk, bv, biasQKV);

  // QKV projection: M=4096 (32 m-tiles), N=2304 (18 n-tiles); nm/8 = 4
  gemm_mfma<0><<<dim3((MTOT / 128) * (NQKV / 128)), 256, 0, stream>>>(
      Xb, WT, biasQKV, QKVb, MTOT, NQKV, HIDDEN, (MTOT / 128) / 8);
  transpose_v_kernel<<<dim3(MTOT / 32, HD / 32), 256, 0, stream>>>(
      QKVb + HIDDEN + HD, Vt);
  flash_mfma<<<dim3(SEQ / 128, HEADS, BSZ), 256, 0, stream>>>(
      QKVb, Vt, mask, flags, Ab);
  // O projection: M=4096 (32 m-tiles), N=2048 (16 n-tiles)
  gemm_mfma<1><<<dim3((MTOT / 128) * (HIDDEN / 128)), 256, 0, stream>>>(
      Ab, WoT, bo, out, MTOT, HIDDEN, HIDDEN, (MTOT / 128) / 8);
}